// Round 6
// baseline (491.206 us; speedup 1.0000x reference)
//
#include <hip/hip_runtime.h>
#include <math.h>

#define VOCAB 50000
#define DW 300
#define DH 50
#define G4 200
#define BATCH 1024
#define TMAX 200
#define OUTC 4

// workspace layout (floats):
//   emb_proj : VOCAB*G4   = 10,000,000  (plain gate-major cols: u = g*50+unit)
//   w_T      : DW*G4      =     60,000  (w_ih transposed)
//   w2p      : 2*DH*104   =     10,400  (per (wave,unit): 2 gate rows padded to 52)

// ---------------------------------------------------------------------------
__global__ __launch_bounds__(256) void prep_kernel(
    const float* __restrict__ w_ih, const float* __restrict__ w_hh,
    float* __restrict__ w_T, float* __restrict__ w2p)
{
    int i = blockIdx.x * 256 + threadIdx.x;
    if (i < G4 * DW) {                       // transpose w_ih [200][300] -> [300][200]
        int u = i / DW, k = i % DW;
        w_T[k * G4 + u] = w_ih[i];
    }
    int j = i - G4 * DW;
    if (j >= 0 && j < 2 * DH * 104) {        // j = (w*50+ll)*104 + g2*52 + k
        int k = j % 52, rest = j / 52;
        int g2 = rest & 1, wl = rest >> 1;
        int wv = wl / DH, ll = wl % DH;
        int gate = 2 * wv + g2;
        w2p[j] = (k < DH) ? w_hh[(gate * DH + ll) * DH + k] : 0.f;
    }
}

// ---------------------------------------------------------------------------
// proj v3: tile 4Mx4N per thread, ~95 VGPR total (16 acc + 32 e + 32 w pingpong)
// -- fits UNDER the compiler's hard 128-VGPR budget (R4/R5: attributes cannot
// raise it; 8x8 tile spilled 40 MB to scratch). Both operands double-buffered;
// e reads are 50-lane broadcast, w reads coalesced. 2500 blocks x 256.
__device__ __forceinline__ float getc(const float4& v, int kc) {
    return kc == 0 ? v.x : kc == 1 ? v.y : kc == 2 ? v.z : v.w;
}

__device__ __forceinline__ void loadE4(const float* eb, int k4, float4 (&e)[4]) {
#pragma unroll
    for (int m = 0; m < 4; m++)
        e[m] = *(const float4*)(eb + m * DW + k4 * 4);
}
__device__ __forceinline__ void loadW4(const float* wb, int k4, float4 (&w)[4]) {
#pragma unroll
    for (int j = 0; j < 4; j++)
        w[j] = *(const float4*)(wb + (size_t)(k4 * 4 + j) * G4);
}
__device__ __forceinline__ void comp4(const float4 (&e)[4], const float4 (&w)[4],
                                      float (&acc)[4][4]) {
#pragma unroll
    for (int j = 0; j < 4; j++)
#pragma unroll
        for (int m = 0; m < 4; m++) {
            float ev = getc(e[m], j);
            acc[m][0] = fmaf(ev, w[j].x, acc[m][0]);
            acc[m][1] = fmaf(ev, w[j].y, acc[m][1]);
            acc[m][2] = fmaf(ev, w[j].z, acc[m][2]);
            acc[m][3] = fmaf(ev, w[j].w, acc[m][3]);
        }
}

__global__ __launch_bounds__(256) void proj_kernel(
    const float* __restrict__ emb, const float* __restrict__ w_T,
    const float* __restrict__ b_ih, const float* __restrict__ b_hh,
    float* __restrict__ emb_proj)
{
    const int tid = threadIdx.x;
    const int tt  = (tid < 250) ? tid : 249;  // 250-255 duplicate 249 (benign)
    const int m_idx = tt / 50;                // 0..4
    const int n_idx = tt % 50;                // 0..49
    const int r0 = blockIdx.x * 20 + m_idx * 4;

    const float* eb = emb + (size_t)r0 * DW;
    const float* wb = w_T + n_idx * 4;

    float acc[4][4];
#pragma unroll
    for (int m = 0; m < 4; m++)
#pragma unroll
        for (int c = 0; c < 4; c++) acc[m][c] = 0.f;

    float4 eC[4], eN[4], wC[4], wN[4];
    loadE4(eb, 0, eC); loadW4(wb, 0, wC);

    for (int k4 = 0; k4 < 74; k4 += 2) {
        loadE4(eb, k4 + 1, eN); loadW4(wb, k4 + 1, wN);
        comp4(eC, wC, acc);
        loadE4(eb, k4 + 2, eC); loadW4(wb, k4 + 2, wC);
        comp4(eN, wN, acc);
    }
    comp4(eC, wC, acc);   // k4 = 74

#pragma unroll
    for (int m = 0; m < 4; m++) {
        float4 st;
        st.x = acc[m][0] + b_ih[n_idx * 4 + 0] + b_hh[n_idx * 4 + 0];
        st.y = acc[m][1] + b_ih[n_idx * 4 + 1] + b_hh[n_idx * 4 + 1];
        st.z = acc[m][2] + b_ih[n_idx * 4 + 2] + b_hh[n_idx * 4 + 2];
        st.w = acc[m][3] + b_ih[n_idx * 4 + 3] + b_hh[n_idx * 4 + 3];
        *(float4*)&emb_proj[(size_t)(r0 + m) * G4 + n_idx * 4] = st;
    }
}

// ---------------------------------------------------------------------------
// lstm v3: TWO waves per batch element (block=128). Wave 0 owns gates i,f of
// unit l; wave 1 owns g,o -- 104 W floats/lane + ~16 overhead, UNDER the
// 128-VGPR wall (the full 208-float W file of R2-R5 can never be allocated;
// the compiler re-fetched W from memory every step -> ~1800 cyc/step).
// Gate sums exchanged via parity-double-buffered LDS (1 barrier/step); both
// waves redundantly run the nonlinearity (bitwise-identical) so h stays in
// registers and broadcasts via readlane. Depth-2 ping-pong gather prefetch;
// unroll-by-2 with branchless freeze (== exact mask semantics, uniform
// barrier count).
__device__ __forceinline__ float tanh_f(float x) {
    float e2 = __expf(fminf(2.f * x, 60.f));
    return (e2 - 1.f) / (e2 + 1.f);
}

__global__ __launch_bounds__(128) void lstm_kernel(
    const int* __restrict__ x, const int* __restrict__ lengs,
    const float* __restrict__ emb_proj, const float* __restrict__ w2p,
    const float* __restrict__ w_out, const float* __restrict__ b_out,
    float* __restrict__ out)
{
    __shared__ int x_s[TMAX];
    __shared__ float2 ex_s[2][2][64];   // [parity][wave][lane]
    __shared__ float h_fin[DH];
    __shared__ float red[OUTC];

    const int tid = threadIdx.x;
    const int wv  = tid >> 6;                 // wave id 0/1 (uniform per wave)
    const int l   = tid & 63;
    const int ll  = (l < DH) ? l : DH - 1;    // lanes 50-63 duplicate 49
    const int b   = blockIdx.x;
    const int len = lengs[b];

    for (int i = tid; i < TMAX; i += 128) x_s[i] = x[b * TMAX + i];

    // 2 gate rows of unit ll for this wave: 26 aligned float4 (104 VGPRs)
    float4 wr[26];
    {
        const float4* wp = (const float4*)w2p + (size_t)(wv * DH + ll) * 26;
#pragma unroll
        for (int i = 0; i < 26; i++) wr[i] = wp[i];
    }
    __syncthreads();

    const float* epA = emb_proj + wv * 100 + ll;        // gate 2*wv
    const float* epB = emb_proj + wv * 100 + 50 + ll;   // gate 2*wv+1

    float hn = 0.f, c = 0.f;
    int tk0 = x_s[0], tk1 = x_s[1];
    float pa0 = epA[(size_t)tk0 * G4], pb0 = epB[(size_t)tk0 * G4];
    float pa1 = epA[(size_t)tk1 * G4], pb1 = epB[(size_t)tk1 * G4];

    const int T2 = (len + 1) & ~1;
    for (int t = 0; t < T2; t += 2) {
        int n2 = (t + 2 < TMAX) ? t + 2 : TMAX - 1;
        int n3 = (t + 3 < TMAX) ? t + 3 : TMAX - 1;
        int tk2 = x_s[n2], tk3 = x_s[n3];

#pragma unroll
        for (int p = 0; p < 2; p++) {         // p=0: step t, p=1: step t+1
            float ga, gb;
            if (p == 0) {
                ga = pa0; gb = pb0;
                pa0 = epA[(size_t)tk2 * G4]; pb0 = epB[(size_t)tk2 * G4];
            } else {
                ga = pa1; gb = pb1;
                pa1 = epA[(size_t)tk3 * G4]; pb1 = epB[(size_t)tk3 * G4];
            }
#pragma unroll
            for (int k = 0; k < DH; k++) {
                float hk = __uint_as_float(
                    __builtin_amdgcn_readlane(__float_as_uint(hn), k));
                ga = fmaf(hk, getc(wr[k >> 2],        k & 3), ga);
                gb = fmaf(hk, getc(wr[13 + (k >> 2)], k & 3), gb);
            }
            ex_s[p][wv][l] = make_float2(ga, gb);
            __syncthreads();
            float2 o = ex_s[p][1 - wv][l];

            float gi = wv ? o.x : ga, gf = wv ? o.y : gb;
            float gg = wv ? ga : o.x, go = wv ? gb : o.y;
            float si = 1.f / (1.f + __expf(-gi));
            float sf = 1.f / (1.f + __expf(-gf));
            float so = 1.f / (1.f + __expf(-go));
            float cn = fmaf(sf, c, si * tanh_f(gg));
            float hh = so * tanh_f(cn);
            bool act = (t + p) < len;          // wave-uniform freeze
            c  = act ? cn : c;
            hn = act ? hh : hn;
        }
    }

    if (tid < DH) h_fin[tid] = hn;             // wave 0 lanes 0..49
    __syncthreads();

    if (tid < OUTC) {
        float lg = b_out[tid];
        const float* wo = w_out + tid * DH;
#pragma unroll
        for (int k = 0; k < DH; k++) lg = fmaf(h_fin[k], wo[k], lg);
        red[tid] = lg;
    }
    __syncthreads();
    if (tid < OUTC) {
        float m = fmaxf(fmaxf(red[0], red[1]), fmaxf(red[2], red[3]));
        float s = 0.f;
#pragma unroll
        for (int j = 0; j < OUTC; j++) s += __expf(red[j] - m);
        out[b * OUTC + tid] = __expf(red[tid] - m) / s;
    }
}

// ---------------------------------------------------------------------------
extern "C" void kernel_launch(void* const* d_in, const int* in_sizes, int n_in,
                              void* d_out, int out_size, void* d_ws, size_t ws_size,
                              hipStream_t stream) {
    const int*   x     = (const int*)d_in[0];
    const int*   lengs = (const int*)d_in[1];
    const float* emb   = (const float*)d_in[2];
    const float* w_ih  = (const float*)d_in[3];
    const float* w_hh  = (const float*)d_in[4];
    const float* b_ih  = (const float*)d_in[5];
    const float* b_hh  = (const float*)d_in[6];
    const float* w_out = (const float*)d_in[7];
    const float* b_out = (const float*)d_in[8];
    float* out = (float*)d_out;

    float* emb_proj = (float*)d_ws;
    float* w_T      = emb_proj + (size_t)VOCAB * G4;
    float* w2p      = w_T + (size_t)DW * G4;

    hipLaunchKernelGGL(prep_kernel, dim3((G4 * DW + 2 * DH * 104 + 255) / 256),
                       dim3(256), 0, stream, w_ih, w_hh, w_T, w2p);
    hipLaunchKernelGGL(proj_kernel, dim3(VOCAB / 20), dim3(256), 0, stream,
                       emb, w_T, b_ih, b_hh, emb_proj);
    hipLaunchKernelGGL(lstm_kernel, dim3(BATCH), dim3(128), 0, stream,
                       x, lengs, emb_proj, w2p, w_out, b_out, out);
}